// Round 12
// baseline (266.698 us; speedup 1.0000x reference)
//
#include <hip/hip_runtime.h>
#include <hip/hip_bf16.h>

// B=128, S=256, E=768, C=4; M = B*S = 32768.
// Launches:
//  memset: logits[32768,4] = 0
//  prep:  qW1 partials (fp32) | W1t8=fp8(W1[768:].T) | W2t8=fp8(W2.T) | segF8=fp8(segments)
//  K2:    H1f8[32768,768]fp8 = gelu(segF8 @ W1t8^T + b1 + sum qW1p[bag])   (fp8-MX, BK=128)
//  K3:    logits += (gelu(H1f8 @ W2t8^T + b2) @ W3)   (fp8-MX, BK=128; layer3 fused, atomic)
//  head:  out[128,4] = aggregate(softmax(logits + b3))

typedef __attribute__((ext_vector_type(8))) short short8;
typedef __attribute__((ext_vector_type(8))) unsigned short ushort8;
typedef __attribute__((ext_vector_type(16))) float f32x16;
typedef __attribute__((ext_vector_type(8))) int i32x8;
typedef __attribute__((ext_vector_type(4))) int i32x4;

__device__ __forceinline__ unsigned short f2bf(float f) {
    union { float f; unsigned int u; } c; c.f = f;
    unsigned int u = c.u;
    unsigned int r = (u + 0x7FFFu + ((u >> 16) & 1u)) >> 16;  // RNE
    return (unsigned short)r;
}
__device__ __forceinline__ float bf2f(unsigned short u) {
    union { unsigned int u; float f; } c; c.u = ((unsigned int)u) << 16;
    return c.f;
}
__device__ __forceinline__ float gelu_fast(float x) {
    float x2 = x * x;
    float y2 = 1.5957691216057308f * (x + 0.044715f * x2 * x);
    float e = __expf(y2);
    float t = 1.0f - 2.0f * __builtin_amdgcn_rcpf(e + 1.0f);
    return 0.5f * x * (1.0f + t);
}

typedef const __attribute__((address_space(1))) void* gas_t;
typedef __attribute__((address_space(3))) void* las_t;
__device__ __forceinline__ void g2l16(const void* g, void* l) {
    __builtin_amdgcn_global_load_lds((gas_t)g, (las_t)l, 16, 0, 0);
}

__device__ __forceinline__ unsigned int f4_to_fp8x4(float a, float b, float c, float d) {
    int lo = __builtin_amdgcn_cvt_pk_fp8_f32(a, b, 0, 0);
    return (unsigned int)__builtin_amdgcn_cvt_pk_fp8_f32(c, d, lo, 1);
}
__device__ __forceinline__ unsigned char f_to_fp8(float a) {
    return (unsigned char)(__builtin_amdgcn_cvt_pk_fp8_f32(a, a, 0, 0) & 0xFF);
}

// ---------------- fused prep kernel ----------------
#define PREP_Q    96
#define PREP_TR1E 240
#define PREP_TR2E 312
#define PREP_END  12600

__global__ __launch_bounds__(256) void prep_kernel(
    const float* __restrict__ segments, unsigned char* __restrict__ segF8,
    const float* __restrict__ W1, unsigned char* __restrict__ W1t8,
    const float* __restrict__ W2, unsigned char* __restrict__ W2t8,
    const float* __restrict__ questions, float* __restrict__ qW1p)
{
    __shared__ __align__(16) char sh[16640];
    const int bid = blockIdx.x, tid = threadIdx.x;

    if (bid < PREP_Q) {
        const int s = bid / 24, rem = bid % 24;
        const int n0 = (rem % 12) * 64, m0 = (rem / 12) * 64;
        float (*As)[64] = (float(*)[64])sh;
        float (*Bs)[64] = (float(*)[64])(sh + 4096);
        const int tn = tid & 15, tm = tid >> 4;
        float acc[4][4] = {};
        const int la_m = tid >> 2;
        const int la_k = (tid & 3) << 2;
        const int lb_k = tid >> 4;
        const int lb_n = (tid & 15) << 2;
        const float* Aptr = questions + (size_t)(m0 + la_m) * 768 + la_k;
        const float* Bptr = W1 + (size_t)lb_k * 768 + n0 + lb_n;
        const int kbeg = s * 192, kend = kbeg + 192;
        for (int k0 = kbeg; k0 < kend; k0 += 16) {
            float4 av = *(const float4*)(Aptr + k0);
            float4 bv = *(const float4*)(Bptr + (size_t)k0 * 768);
            As[la_k + 0][la_m] = av.x;
            As[la_k + 1][la_m] = av.y;
            As[la_k + 2][la_m] = av.z;
            As[la_k + 3][la_m] = av.w;
            *(float4*)&Bs[lb_k][lb_n] = bv;
            __syncthreads();
            #pragma unroll
            for (int k = 0; k < 16; k++) {
                float4 a = *(const float4*)&As[k][tm << 2];
                float4 b = *(const float4*)&Bs[k][tn << 2];
                float ar[4] = {a.x, a.y, a.z, a.w};
                float br[4] = {b.x, b.y, b.z, b.w};
                #pragma unroll
                for (int i = 0; i < 4; i++)
                    #pragma unroll
                    for (int j = 0; j < 4; j++)
                        acc[i][j] += ar[i] * br[j];
            }
            __syncthreads();
        }
        float* outp = qW1p + (size_t)s * 128 * 768;
        #pragma unroll
        for (int i = 0; i < 4; i++) {
            int row = m0 + (tm << 2) + i;
            int colBase = n0 + (tn << 2);
            *(float4*)&outp[(size_t)row * 768 + colBase] =
                make_float4(acc[i][0], acc[i][1], acc[i][2], acc[i][3]);
        }
        return;
    }

    if (bid < PREP_TR2E) {
        const float* in; unsigned char* outp; int R, C, bx, by;
        if (bid < PREP_TR1E) {
            int idx = bid - PREP_Q; bx = idx % 12; by = idx / 12;
            in = W1 + 768 * 768; outp = W1t8; R = 768; C = 768;
        } else {
            int idx = bid - PREP_TR1E; bx = idx % 6; by = idx / 6;
            in = W2; outp = W2t8; R = 768; C = 384;
        }
        float (*t)[65] = (float(*)[65])sh;
        int r0 = by * 64, c0 = bx * 64;
        int tx = tid & 63, ty = tid >> 6;
        #pragma unroll
        for (int p = 0; p < 16; p++) {
            int row = ty * 16 + p;
            t[row][tx] = in[(size_t)(r0 + row) * C + c0 + tx];
        }
        __syncthreads();
        #pragma unroll
        for (int p = 0; p < 16; p++) {
            int orow = ty * 16 + p;
            outp[(size_t)(c0 + orow) * R + r0 + tx] = f_to_fp8(t[tx][orow]);
        }
        return;
    }

    {
        long i = (long)(bid - PREP_TR2E) * 256 + tid;
        const float4* in = (const float4*)segments;
        float4 a = in[2 * i], b = in[2 * i + 1];
        unsigned int lo = f4_to_fp8x4(a.x, a.y, a.z, a.w);
        unsigned int hi = f4_to_fp8x4(b.x, b.y, b.z, b.w);
        *(uint2*)(segF8 + i * 8) = make_uint2(lo, hi);
    }
}

// ---------------- fp8 frag read helper (BK=128 layout) ----------------
// LDS [128 rows][128 B]; position chunk p holds source chunk p^ (row&7).
// Operand for k-step s (0/1), lane quad fq: source chunks s*4+fq*2, +1.
__device__ __forceinline__ i32x8 frag_f8(const unsigned char* base, int row, int s, int fq) {
    const int key = row & 7;
    const int c0 = s * 4 + fq * 2;
    i32x4 lo = *(const i32x4*)&base[row * 128 + ((c0 + 0) ^ key) * 16];
    i32x4 hi = *(const i32x4*)&base[row * 128 + ((c0 + 1) ^ key) * 16];
    i32x8 v;
    v[0] = lo[0]; v[1] = lo[1]; v[2] = lo[2]; v[3] = lo[3];
    v[4] = hi[0]; v[5] = hi[1]; v[6] = hi[2]; v[7] = hi[3];
    return v;
}

// ---------------- K2: fp8-MX GEMM, BK=128, fp8 output ----------------
__global__ __launch_bounds__(256) void k2_f8(
    const unsigned char* __restrict__ A8,    // [M,768] fp8
    const unsigned char* __restrict__ Bt8,   // [768,768] fp8
    const float* __restrict__ bias,          // [768]
    const float* __restrict__ rowAdd,        // [4][128,768] partials
    unsigned char* __restrict__ Cout,        // [M,768] fp8
    int M, int N, int K)
{
    __shared__ __align__(16) unsigned char smem8[32768];
    unsigned char* As = smem8;             // [128][128B] swizzled
    unsigned char* Bs = smem8 + 16384;     // [128][128B]
    const int tid = threadIdx.x;
    const int wave = tid >> 6, lane = tid & 63;
    const int m0 = blockIdx.y * 128, n0 = blockIdx.x * 128;
    const int wm = (wave & 1) * 64, wn = (wave >> 1) * 64;

    f32x16 acc[2][2] = {};

    const int srow = tid >> 3;                       // 0..31
    const int schunk = (tid & 7) ^ (srow & 7);
    const unsigned char* Ag = A8 + (size_t)(m0 + srow) * K + schunk * 16;
    const unsigned char* Bg = Bt8 + (size_t)(n0 + srow) * K + schunk * 16;
    unsigned char* Al = As + tid * 16;
    unsigned char* Bl = Bs + tid * 16;

    const int fm = lane & 31, fq = lane >> 5;

    for (int k0 = 0; k0 < K; k0 += 128) {
        #pragma unroll
        for (int r = 0; r < 4; r++) {
            g2l16(Ag + k0 + (size_t)(32 * r) * K, Al + r * 4096);
            g2l16(Bg + k0 + (size_t)(32 * r) * K, Bl + r * 4096);
        }
        __syncthreads();

        #pragma unroll
        for (int s = 0; s < 2; s++) {
            i32x8 av[2], bv[2];
            #pragma unroll
            for (int i = 0; i < 2; i++) av[i] = frag_f8(As, wm + i * 32 + fm, s, fq);
            #pragma unroll
            for (int j = 0; j < 2; j++) bv[j] = frag_f8(Bs, wn + j * 32 + fm, s, fq);
            #pragma unroll
            for (int i = 0; i < 2; i++)
                #pragma unroll
                for (int j = 0; j < 2; j++)
                    acc[i][j] = __builtin_amdgcn_mfma_scale_f32_32x32x64_f8f6f4(
                        av[i], bv[j], acc[i][j], 0, 0, 0, 127, 0, 127);
        }
        __syncthreads();
    }

    // Epilogue: C/D col=lane&31, row=(reg&3)+8*(reg>>2)+4*(lane>>5); gelu -> fp8
    const float* radd = rowAdd + (size_t)(m0 >> 8) * N;
    #pragma unroll
    for (int j = 0; j < 2; j++) {
        int coll = wn + j * 32 + fm;
        int col = n0 + coll;
        float add = bias[col] + radd[col] + radd[col + 98304] +
                    radd[col + 2 * 98304] + radd[col + 3 * 98304];
        #pragma unroll
        for (int i = 0; i < 2; i++) {
            int rbase = wm + i * 32 + 4 * fq;
            #pragma unroll
            for (int reg = 0; reg < 16; reg++) {
                int rowl = rbase + (reg & 3) + 8 * (reg >> 2);
                smem8[rowl * 128 + coll] = f_to_fp8(gelu_fast(acc[i][j][reg] + add));
            }
        }
    }
    __syncthreads();
    #pragma unroll
    for (int it = 0; it < 4; it++) {
        int idx = it * 256 + tid;
        int r = idx >> 3, cc = (idx & 7) * 16;
        *(uint4*)&Cout[(size_t)(m0 + r) * N + n0 + cc] =
            *(const uint4*)&smem8[r * 128 + cc];
    }
}

// ---------------- K3: fp8-MX GEMM, BK=128, fused layer3 -> atomic logits ----
__global__ __launch_bounds__(256) void k3_f8_logits(
    const unsigned char* __restrict__ A8,    // [M,768] fp8 (H1)
    const unsigned char* __restrict__ Bt8,   // [384,768] fp8 (W2t)
    const float* __restrict__ bias,          // [384]
    const float* __restrict__ W3,            // [384,4]
    float* __restrict__ logits,              // [M,4] fp32 (pre-zeroed)
    int M, int N, int K)
{
    __shared__ __align__(16) unsigned char smem8[32768 + 2048];
    unsigned char* As = smem8;
    unsigned char* Bs = smem8 + 16384;
    unsigned short* cst = (unsigned short*)smem8;        // 128x128 bf16 H2 tile (32KB)
    float4* w3l = (float4*)(smem8 + 32768);              // [128] W3 chunk
    const int tid = threadIdx.x;
    const int wave = tid >> 6, lane = tid & 63;
    const int m0 = blockIdx.y * 128, n0 = blockIdx.x * 128;
    const int wm = (wave & 1) * 64, wn = (wave >> 1) * 64;

    f32x16 acc[2][2] = {};

    const int srow = tid >> 3;
    const int schunk = (tid & 7) ^ (srow & 7);
    const unsigned char* Ag = A8 + (size_t)(m0 + srow) * K + schunk * 16;
    const unsigned char* Bg = Bt8 + (size_t)(n0 + srow) * K + schunk * 16;
    unsigned char* Al = As + tid * 16;
    unsigned char* Bl = Bs + tid * 16;

    const int fm = lane & 31, fq = lane >> 5;

    for (int k0 = 0; k0 < K; k0 += 128) {
        #pragma unroll
        for (int r = 0; r < 4; r++) {
            g2l16(Ag + k0 + (size_t)(32 * r) * K, Al + r * 4096);
            g2l16(Bg + k0 + (size_t)(32 * r) * K, Bl + r * 4096);
        }
        __syncthreads();

        #pragma unroll
        for (int s = 0; s < 2; s++) {
            i32x8 av[2], bv[2];
            #pragma unroll
            for (int i = 0; i < 2; i++) av[i] = frag_f8(As, wm + i * 32 + fm, s, fq);
            #pragma unroll
            for (int j = 0; j < 2; j++) bv[j] = frag_f8(Bs, wn + j * 32 + fm, s, fq);
            #pragma unroll
            for (int i = 0; i < 2; i++)
                #pragma unroll
                for (int j = 0; j < 2; j++)
                    acc[i][j] = __builtin_amdgcn_mfma_scale_f32_32x32x64_f8f6f4(
                        av[i], bv[j], acc[i][j], 0, 0, 0, 127, 0, 127);
        }
        __syncthreads();
    }

    // H2 tile (bf16, matches r11 head input precision) into LDS
    #pragma unroll
    for (int j = 0; j < 2; j++) {
        int coll = wn + j * 32 + fm;
        float add = bias[n0 + coll];
        #pragma unroll
        for (int i = 0; i < 2; i++) {
            int rbase = wm + i * 32 + 4 * fq;
            #pragma unroll
            for (int reg = 0; reg < 16; reg++) {
                int rowl = rbase + (reg & 3) + 8 * (reg >> 2);
                cst[rowl * 128 + coll] = f2bf(gelu_fast(acc[i][j][reg] + add));
            }
        }
    }
    if (tid < 128) w3l[tid] = ((const float4*)W3)[n0 + tid];
    __syncthreads();

    // layer3 partial: each thread does 2 (row, class) dots over this 128-col chunk
    #pragma unroll
    for (int it = 0; it < 2; it++) {
        int idx = it * 256 + tid;
        int r = idx >> 2, c = idx & 3;
        float sum = 0.f;
        #pragma unroll 8
        for (int cc = 0; cc < 128; cc++) {
            float4 w = w3l[cc];
            float wc = (c == 0) ? w.x : (c == 1) ? w.y : (c == 2) ? w.z : w.w;
            sum += bf2f(cst[r * 128 + cc]) * wc;
        }
        atomicAdd(&logits[(size_t)(m0 + r) * 4 + c], sum);
    }
}

// ---------------- head: softmax + aggregation ----------------
__device__ __forceinline__ float4 f4mul(float4 a, float4 b) {
    return make_float4(a.x * b.x, a.y * b.y, a.z * b.z, a.w * b.w);
}
__device__ float4 scan_prod(float4 v, float4* buf, int tid) {
    __syncthreads();
    buf[tid] = v;
    __syncthreads();
    #pragma unroll
    for (int off = 1; off < 256; off <<= 1) {
        float4 o = (tid >= off) ? buf[tid - off] : make_float4(1.f, 1.f, 1.f, 1.f);
        __syncthreads();
        v = f4mul(v, o);
        buf[tid] = v;
        __syncthreads();
    }
    return v;
}

__global__ __launch_bounds__(256) void head_kernel(
    const float* __restrict__ logits, const float* __restrict__ b3,
    const int* __restrict__ nseg, float* __restrict__ out)
{
    __shared__ float4 buf[256];
    const int b = blockIdx.x, tid = threadIdx.x;

    float4 z = ((const float4*)logits)[b * 256 + tid];
    z.x += b3[0]; z.y += b3[1]; z.z += b3[2]; z.w += b3[3];
    float m = fmaxf(fmaxf(z.x, z.y), fmaxf(z.z, z.w));
    float e0 = __expf(z.x - m), e1 = __expf(z.y - m),
          e2 = __expf(z.z - m), e3 = __expf(z.w - m);
    float inv = 1.0f / (e0 + e1 + e2 + e3);
    float4 p = make_float4(e0 * inv, e1 * inv, e2 * inv, e3 * inv);

    const int n = nseg[b];
    const float4 ones = make_float4(1.f, 1.f, 1.f, 1.f);
    bool msk = tid < n;
    float s1 = p.x, s2 = s1 + p.y, s3 = s2 + p.z;
    float4 sm = msk ? make_float4(0.f, s1, s2, s3) : ones;

    scan_prod(sm, buf, tid);
    float4 pfx = (tid > 0) ? buf[tid - 1] : ones;
    __syncthreads();

    buf[255 - tid] = sm;
    __syncthreads();
    float4 rsm = buf[tid];
    scan_prod(rsm, buf, tid);
    float4 sfx = (tid < 255) ? buf[254 - tid] : ones;

    float4 L = f4mul(pfx, sfx);
    float4 cpL = scan_prod(L, buf, tid);

    float4 term = msk ? f4mul(p, cpL) : make_float4(0.f, 0.f, 0.f, 0.f);
    float4 pm = msk ? p : ones;

    __syncthreads();
    buf[tid] = term;
    __syncthreads();
    for (int off = 128; off > 0; off >>= 1) {
        if (tid < off) {
            float4 a = buf[tid], c = buf[tid + off];
            buf[tid] = make_float4(a.x + c.x, a.y + c.y, a.z + c.z, a.w + c.w);
        }
        __syncthreads();
    }
    float4 sum_t = buf[0];
    __syncthreads();

    buf[tid] = pm;
    __syncthreads();
    for (int off = 128; off > 0; off >>= 1) {
        if (tid < off) buf[tid] = f4mul(buf[tid], buf[tid + off]);
        __syncthreads();
    }
    if (tid == 0) {
        float4 pr = buf[0];
        ((float4*)out)[b] = make_float4(0.25f * sum_t.x + pr.x,
                                        0.25f * sum_t.y + pr.y,
                                        0.25f * sum_t.z + pr.z,
                                        0.25f * sum_t.w + pr.w);
    }
}

extern "C" void kernel_launch(void* const* d_in, const int* in_sizes, int n_in,
                              void* d_out, int out_size, void* d_ws, size_t ws_size,
                              hipStream_t stream) {
    (void)in_sizes; (void)n_in; (void)out_size; (void)ws_size;
    const float* questions = (const float*)d_in[0];
    const float* segments  = (const float*)d_in[1];
    const float* W1 = (const float*)d_in[2];
    const float* b1 = (const float*)d_in[3];
    const float* W2 = (const float*)d_in[4];
    const float* b2 = (const float*)d_in[5];
    const float* W3 = (const float*)d_in[6];
    const float* b3 = (const float*)d_in[7];
    const int*  nseg = (const int*)d_in[8];
    float* out = (float*)d_out;

    char* w = (char*)d_ws;
    float* qW1p = (float*)w;                   w += (size_t)4 * 128 * 768 * 4;
    unsigned char*  W1t8 = (unsigned char*)w;  w += (size_t)768 * 768;
    unsigned char*  W2t8 = (unsigned char*)w;  w += (size_t)384 * 768;
    unsigned char*  segF8 = (unsigned char*)w; w += (size_t)32768 * 768;
    unsigned char*  H1f8 = (unsigned char*)w;  w += (size_t)32768 * 768;
    float* logits = (float*)w;                 w += (size_t)32768 * 4 * 4;

    hipMemsetAsync(logits, 0, (size_t)32768 * 4 * 4, stream);
    prep_kernel<<<PREP_END, 256, 0, stream>>>(
        segments, segF8, W1, W1t8, W2, W2t8, questions, qW1p);
    k2_f8<<<dim3(6, 256), 256, 0, stream>>>(
        segF8, W1t8, b1, qW1p, H1f8, 32768, 768, 768);
    k3_f8_logits<<<dim3(3, 256), 256, 0, stream>>>(
        H1f8, W2t8, b2, W3, logits, 32768, 384, 768);
    head_kernel<<<128, 256, 0, stream>>>(logits, b3, nseg, out);
}

// Round 13
// 246.315 us; speedup vs baseline: 1.0828x; 1.0828x over previous
//
#include <hip/hip_runtime.h>
#include <hip/hip_bf16.h>

// B=128, S=256, E=768, C=4; M = B*S = 32768.
// r11 configuration (measured optimum 245 us) — r12's three deltas (BK=128,
// fused layer3 w/ atomics, extra memset launch) all reverted after +21us regression.
// 4 launches:
//  prep:  qW1 partials (fp32) | W1t8=fp8(W1[768:].T) | W2t8=fp8(W2.T) | segF8=fp8(segments)
//  K2:    H1f8[32768,768]fp8 = gelu(segF8 @ W1t8^T + b1 + sum qW1p[bag])   (fp8-MX, BK=64)
//  K3:    H2b[32768,384]bf16 = gelu(H1f8 @ W2t8^T + b2)                    (fp8-MX, BK=64)
//  head:  out[128,4] = aggregate(softmax(H2b @ W3 + b3))

typedef __attribute__((ext_vector_type(8))) short short8;
typedef __attribute__((ext_vector_type(8))) unsigned short ushort8;
typedef __attribute__((ext_vector_type(16))) float f32x16;
typedef __attribute__((ext_vector_type(8))) int i32x8;
typedef __attribute__((ext_vector_type(4))) int i32x4;

__device__ __forceinline__ unsigned short f2bf(float f) {
    union { float f; unsigned int u; } c; c.f = f;
    unsigned int u = c.u;
    unsigned int r = (u + 0x7FFFu + ((u >> 16) & 1u)) >> 16;  // RNE
    return (unsigned short)r;
}
__device__ __forceinline__ float bf2f(unsigned short u) {
    union { unsigned int u; float f; } c; c.u = ((unsigned int)u) << 16;
    return c.f;
}
__device__ __forceinline__ float gelu_fast(float x) {
    float x2 = x * x;
    float y2 = 1.5957691216057308f * (x + 0.044715f * x2 * x);
    float e = __expf(y2);
    float t = 1.0f - 2.0f * __builtin_amdgcn_rcpf(e + 1.0f);
    return 0.5f * x * (1.0f + t);
}

typedef const __attribute__((address_space(1))) void* gas_t;
typedef __attribute__((address_space(3))) void* las_t;
__device__ __forceinline__ void g2l16(const void* g, void* l) {
    __builtin_amdgcn_global_load_lds((gas_t)g, (las_t)l, 16, 0, 0);
}

__device__ __forceinline__ unsigned int f4_to_fp8x4(float a, float b, float c, float d) {
    int lo = __builtin_amdgcn_cvt_pk_fp8_f32(a, b, 0, 0);
    return (unsigned int)__builtin_amdgcn_cvt_pk_fp8_f32(c, d, lo, 1);
}
__device__ __forceinline__ unsigned char f_to_fp8(float a) {
    return (unsigned char)(__builtin_amdgcn_cvt_pk_fp8_f32(a, a, 0, 0) & 0xFF);
}

// ---------------- fused prep kernel ----------------
#define PREP_Q    96
#define PREP_TR1E 240
#define PREP_TR2E 312
#define PREP_END  12600

__global__ __launch_bounds__(256) void prep_kernel(
    const float* __restrict__ segments, unsigned char* __restrict__ segF8,
    const float* __restrict__ W1, unsigned char* __restrict__ W1t8,
    const float* __restrict__ W2, unsigned char* __restrict__ W2t8,
    const float* __restrict__ questions, float* __restrict__ qW1p)
{
    __shared__ __align__(16) char sh[16640];
    const int bid = blockIdx.x, tid = threadIdx.x;

    if (bid < PREP_Q) {
        const int s = bid / 24, rem = bid % 24;
        const int n0 = (rem % 12) * 64, m0 = (rem / 12) * 64;
        float (*As)[64] = (float(*)[64])sh;
        float (*Bs)[64] = (float(*)[64])(sh + 4096);
        const int tn = tid & 15, tm = tid >> 4;
        float acc[4][4] = {};
        const int la_m = tid >> 2;
        const int la_k = (tid & 3) << 2;
        const int lb_k = tid >> 4;
        const int lb_n = (tid & 15) << 2;
        const float* Aptr = questions + (size_t)(m0 + la_m) * 768 + la_k;
        const float* Bptr = W1 + (size_t)lb_k * 768 + n0 + lb_n;
        const int kbeg = s * 192, kend = kbeg + 192;
        for (int k0 = kbeg; k0 < kend; k0 += 16) {
            float4 av = *(const float4*)(Aptr + k0);
            float4 bv = *(const float4*)(Bptr + (size_t)k0 * 768);
            As[la_k + 0][la_m] = av.x;
            As[la_k + 1][la_m] = av.y;
            As[la_k + 2][la_m] = av.z;
            As[la_k + 3][la_m] = av.w;
            *(float4*)&Bs[lb_k][lb_n] = bv;
            __syncthreads();
            #pragma unroll
            for (int k = 0; k < 16; k++) {
                float4 a = *(const float4*)&As[k][tm << 2];
                float4 b = *(const float4*)&Bs[k][tn << 2];
                float ar[4] = {a.x, a.y, a.z, a.w};
                float br[4] = {b.x, b.y, b.z, b.w};
                #pragma unroll
                for (int i = 0; i < 4; i++)
                    #pragma unroll
                    for (int j = 0; j < 4; j++)
                        acc[i][j] += ar[i] * br[j];
            }
            __syncthreads();
        }
        float* outp = qW1p + (size_t)s * 128 * 768;
        #pragma unroll
        for (int i = 0; i < 4; i++) {
            int row = m0 + (tm << 2) + i;
            int colBase = n0 + (tn << 2);
            *(float4*)&outp[(size_t)row * 768 + colBase] =
                make_float4(acc[i][0], acc[i][1], acc[i][2], acc[i][3]);
        }
        return;
    }

    if (bid < PREP_TR2E) {
        // transpose 64x64 tile -> fp8 bytes
        const float* in; unsigned char* outp; int R, C, bx, by;
        if (bid < PREP_TR1E) {
            int idx = bid - PREP_Q; bx = idx % 12; by = idx / 12;
            in = W1 + 768 * 768; outp = W1t8; R = 768; C = 768;
        } else {
            int idx = bid - PREP_TR1E; bx = idx % 6; by = idx / 6;
            in = W2; outp = W2t8; R = 768; C = 384;
        }
        float (*t)[65] = (float(*)[65])sh;
        int r0 = by * 64, c0 = bx * 64;
        int tx = tid & 63, ty = tid >> 6;
        #pragma unroll
        for (int p = 0; p < 16; p++) {
            int row = ty * 16 + p;
            t[row][tx] = in[(size_t)(r0 + row) * C + c0 + tx];
        }
        __syncthreads();
        #pragma unroll
        for (int p = 0; p < 16; p++) {
            int orow = ty * 16 + p;
            outp[(size_t)(c0 + orow) * R + r0 + tx] = f_to_fp8(t[tx][orow]);
        }
        return;
    }

    // conv: segments fp32 -> segF8 fp8 (8 elems/thread)
    {
        long i = (long)(bid - PREP_TR2E) * 256 + tid;
        const float4* in = (const float4*)segments;
        float4 a = in[2 * i], b = in[2 * i + 1];
        unsigned int lo = f4_to_fp8x4(a.x, a.y, a.z, a.w);
        unsigned int hi = f4_to_fp8x4(b.x, b.y, b.z, b.w);
        *(uint2*)(segF8 + i * 8) = make_uint2(lo, hi);
    }
}

// ---------------- fp8 MX-scaled MFMA GEMM ----------------
// C[M,N] = gelu(A8[M,K] @ Bt8[N,K]^T + bias + optional sum qW1p[bag])
// OUT8=1: output fp8 bytes; OUT8=0: output bf16.
// 128x128 block, 4 waves, wave 64x64 = 2x2 of 32x32x64 f8f6f4 (unit scales), BK=64.
template<int OUT8>
__global__ __launch_bounds__(256) void mfma_gemm_f8(
    const unsigned char* __restrict__ A8,    // [M,K] fp8
    const unsigned char* __restrict__ Bt8,   // [N,K] fp8
    const float* __restrict__ bias,          // [N]
    const float* __restrict__ rowAdd,        // [4][128,N] partials or null
    void* __restrict__ CoutV,                // [M,N] fp8 or bf16
    int M, int N, int K)
{
    __shared__ __align__(16) unsigned char smem8[32768];
    unsigned char* As = smem8;             // [128][64B] swizzled (8KB)
    unsigned char* Bs = smem8 + 8192;      // [128][64B] (8KB)
    const int tid = threadIdx.x;
    const int wave = tid >> 6, lane = tid & 63;
    const int m0 = blockIdx.y * 128, n0 = blockIdx.x * 128;
    const int wm = (wave & 1) * 64, wn = (wave >> 1) * 64;

    f32x16 acc[2][2] = {};

    const int srow = tid >> 2;
    const int schunk = (tid & 3) ^ ((srow >> 1) & 3);
    const unsigned char* Ag = A8 + (size_t)(m0 + srow) * K + schunk * 16;
    const unsigned char* Bg = Bt8 + (size_t)(n0 + srow) * K + schunk * 16;
    unsigned char* Al = As + tid * 16;
    unsigned char* Bl = Bs + tid * 16;

    const int fm = lane & 31, fq = lane >> 5;

    for (int k0 = 0; k0 < K; k0 += 64) {
        g2l16(Ag + k0, Al);
        g2l16(Ag + (size_t)64 * K + k0, Al + 4096);
        g2l16(Bg + k0, Bl);
        g2l16(Bg + (size_t)64 * K + k0, Bl + 4096);
        __syncthreads();

        i32x8 av[2], bv[2];
        #pragma unroll
        for (int i = 0; i < 2; i++) {
            int rw = wm + i * 32 + fm, key = (rw >> 1) & 3;
            i32x4 lo = *(const i32x4*)&As[rw * 64 + (((fq << 1) | 0) ^ key) * 16];
            i32x4 hi = *(const i32x4*)&As[rw * 64 + (((fq << 1) | 1) ^ key) * 16];
            av[i][0] = lo[0]; av[i][1] = lo[1]; av[i][2] = lo[2]; av[i][3] = lo[3];
            av[i][4] = hi[0]; av[i][5] = hi[1]; av[i][6] = hi[2]; av[i][7] = hi[3];
        }
        #pragma unroll
        for (int j = 0; j < 2; j++) {
            int rw = wn + j * 32 + fm, key = (rw >> 1) & 3;
            i32x4 lo = *(const i32x4*)&Bs[rw * 64 + (((fq << 1) | 0) ^ key) * 16];
            i32x4 hi = *(const i32x4*)&Bs[rw * 64 + (((fq << 1) | 1) ^ key) * 16];
            bv[j][0] = lo[0]; bv[j][1] = lo[1]; bv[j][2] = lo[2]; bv[j][3] = lo[3];
            bv[j][4] = hi[0]; bv[j][5] = hi[1]; bv[j][6] = hi[2]; bv[j][7] = hi[3];
        }
        #pragma unroll
        for (int i = 0; i < 2; i++)
            #pragma unroll
            for (int j = 0; j < 2; j++)
                acc[i][j] = __builtin_amdgcn_mfma_scale_f32_32x32x64_f8f6f4(
                    av[i], bv[j], acc[i][j], 0, 0,   // cbsz=fp8, blgp=fp8
                    0, 127, 0, 127);                 // unit e8m0 scales
        __syncthreads();
    }

    // Epilogue (C/D: col=lane&31, row=(reg&3)+8*(reg>>2)+4*(lane>>5)), gelu
    #pragma unroll
    for (int j = 0; j < 2; j++) {
        int coll = wn + j * 32 + fm;
        int col = n0 + coll;
        float add = bias[col];
        if (rowAdd) {
            const float* radd = rowAdd + (size_t)(m0 >> 8) * N;
            add += radd[col] + radd[col + 98304] +
                   radd[col + 2 * 98304] + radd[col + 3 * 98304];
        }
        #pragma unroll
        for (int i = 0; i < 2; i++) {
            int rbase = wm + i * 32 + 4 * fq;
            #pragma unroll
            for (int reg = 0; reg < 16; reg++) {
                int rowl = rbase + (reg & 3) + 8 * (reg >> 2);
                float v = gelu_fast(acc[i][j][reg] + add);
                if (OUT8) smem8[rowl * 128 + coll] = f_to_fp8(v);
                else ((unsigned short*)smem8)[rowl * 128 + coll] = f2bf(v);
            }
        }
    }
    __syncthreads();
    if (OUT8) {
        unsigned char* Cout = (unsigned char*)CoutV;
        #pragma unroll
        for (int it = 0; it < 4; it++) {
            int idx = it * 256 + tid;
            int r = idx >> 3, cc = (idx & 7) * 16;
            *(uint4*)&Cout[(size_t)(m0 + r) * N + n0 + cc] =
                *(const uint4*)&smem8[r * 128 + cc];
        }
    } else {
        unsigned short* Cout = (unsigned short*)CoutV;
        #pragma unroll
        for (int it = 0; it < 8; it++) {
            int idx = it * 256 + tid;
            int r = idx >> 4, cc = (idx & 15) * 8;
            *(ushort8*)&Cout[(size_t)(m0 + r) * N + n0 + cc] =
                *(const ushort8*)&((unsigned short*)smem8)[r * 128 + cc];
        }
    }
}

// ---------------- fused head: layer3 + softmax + aggregation ----------------
__device__ __forceinline__ float4 f4mul(float4 a, float4 b) {
    return make_float4(a.x * b.x, a.y * b.y, a.z * b.z, a.w * b.w);
}
__device__ float4 scan_prod(float4 v, float4* buf, int tid) {
    __syncthreads();
    buf[tid] = v;
    __syncthreads();
    #pragma unroll
    for (int off = 1; off < 256; off <<= 1) {
        float4 o = (tid >= off) ? buf[tid - off] : make_float4(1.f, 1.f, 1.f, 1.f);
        __syncthreads();
        v = f4mul(v, o);
        buf[tid] = v;
        __syncthreads();
    }
    return v;
}

__global__ __launch_bounds__(256) void head_kernel(
    const unsigned short* __restrict__ H2, const float* __restrict__ W3,
    const float* __restrict__ b3, const int* __restrict__ nseg,
    float* __restrict__ out)
{
    __shared__ float4 buf[256];
    __shared__ float4 w3s[384];
    const int b = blockIdx.x, tid = threadIdx.x;
    for (int i = tid; i < 384; i += 256) w3s[i] = ((const float4*)W3)[i];
    __syncthreads();

    const unsigned short* hrow = H2 + (size_t)(b * 256 + tid) * 384;
    float4 acc = make_float4(b3[0], b3[1], b3[2], b3[3]);
    #pragma unroll
    for (int kk = 0; kk < 48; kk++) {
        ushort8 u = *(const ushort8*)(hrow + kk * 8);
        #pragma unroll
        for (int j = 0; j < 8; j++) {
            float h = bf2f(u[j]);
            float4 w = w3s[kk * 8 + j];
            acc.x += h * w.x; acc.y += h * w.y; acc.z += h * w.z; acc.w += h * w.w;
        }
    }
    float m = fmaxf(fmaxf(acc.x, acc.y), fmaxf(acc.z, acc.w));
    float e0 = __expf(acc.x - m), e1 = __expf(acc.y - m),
          e2 = __expf(acc.z - m), e3 = __expf(acc.w - m);
    float inv = 1.0f / (e0 + e1 + e2 + e3);
    float4 p = make_float4(e0 * inv, e1 * inv, e2 * inv, e3 * inv);

    const int n = nseg[b];
    const float4 ones = make_float4(1.f, 1.f, 1.f, 1.f);
    bool msk = tid < n;
    float s1 = p.x, s2 = s1 + p.y, s3 = s2 + p.z;
    float4 sm = msk ? make_float4(0.f, s1, s2, s3) : ones;

    scan_prod(sm, buf, tid);
    float4 pfx = (tid > 0) ? buf[tid - 1] : ones;
    __syncthreads();

    buf[255 - tid] = sm;
    __syncthreads();
    float4 rsm = buf[tid];
    scan_prod(rsm, buf, tid);
    float4 sfx = (tid < 255) ? buf[254 - tid] : ones;

    float4 L = f4mul(pfx, sfx);
    float4 cpL = scan_prod(L, buf, tid);

    float4 term = msk ? f4mul(p, cpL) : make_float4(0.f, 0.f, 0.f, 0.f);
    float4 pm = msk ? p : ones;

    __syncthreads();
    buf[tid] = term;
    __syncthreads();
    for (int off = 128; off > 0; off >>= 1) {
        if (tid < off) {
            float4 a = buf[tid], c = buf[tid + off];
            buf[tid] = make_float4(a.x + c.x, a.y + c.y, a.z + c.z, a.w + c.w);
        }
        __syncthreads();
    }
    float4 sum_t = buf[0];
    __syncthreads();

    buf[tid] = pm;
    __syncthreads();
    for (int off = 128; off > 0; off >>= 1) {
        if (tid < off) buf[tid] = f4mul(buf[tid], buf[tid + off]);
        __syncthreads();
    }
    if (tid == 0) {
        float4 pr = buf[0];
        ((float4*)out)[b] = make_float4(0.25f * sum_t.x + pr.x,
                                        0.25f * sum_t.y + pr.y,
                                        0.25f * sum_t.z + pr.z,
                                        0.25f * sum_t.w + pr.w);
    }
}

extern "C" void kernel_launch(void* const* d_in, const int* in_sizes, int n_in,
                              void* d_out, int out_size, void* d_ws, size_t ws_size,
                              hipStream_t stream) {
    (void)in_sizes; (void)n_in; (void)out_size; (void)ws_size;
    const float* questions = (const float*)d_in[0];
    const float* segments  = (const float*)d_in[1];
    const float* W1 = (const float*)d_in[2];
    const float* b1 = (const float*)d_in[3];
    const float* W2 = (const float*)d_in[4];
    const float* b2 = (const float*)d_in[5];
    const float* W3 = (const float*)d_in[6];
    const float* b3 = (const float*)d_in[7];
    const int*  nseg = (const int*)d_in[8];
    float* out = (float*)d_out;

    char* w = (char*)d_ws;
    float* qW1p = (float*)w;                   w += (size_t)4 * 128 * 768 * 4;
    unsigned char*  W1t8 = (unsigned char*)w;  w += (size_t)768 * 768;
    unsigned char*  W2t8 = (unsigned char*)w;  w += (size_t)384 * 768;
    unsigned char*  segF8 = (unsigned char*)w; w += (size_t)32768 * 768;
    unsigned char*  H1f8 = (unsigned char*)w;  w += (size_t)32768 * 768;
    unsigned short* H2b  = (unsigned short*)w; w += (size_t)32768 * 384 * 2;

    prep_kernel<<<PREP_END, 256, 0, stream>>>(
        segments, segF8, W1, W1t8, W2, W2t8, questions, qW1p);
    // K2 (fp8 -> fp8): grid (n=6, m=256)
    mfma_gemm_f8<1><<<dim3(6, 256), 256, 0, stream>>>(
        segF8, W1t8, b1, qW1p, H1f8, 32768, 768, 768);
    // K3 (fp8 -> bf16): grid (n=3, m=256)
    mfma_gemm_f8<0><<<dim3(3, 256), 256, 0, stream>>>(
        H1f8, W2t8, b2, nullptr, H2b, 32768, 384, 768);
    head_kernel<<<128, 256, 0, stream>>>(H2b, W3, b3, nseg, out);
}